// Round 2
// 426.232 us; speedup vs baseline: 1.0063x; 1.0063x over previous
//
#include <hip/hip_runtime.h>

#define SCALE 128
#define GRID_L 131                        // grid side
#define SLAB (GRID_L * GRID_L)            // 17161 floats per x-slab
#define GRID_V (GRID_L * GRID_L * GRID_L)
#define BATCH 16
#define NPTS 32768                        // points per sample (2^15)
#define NCB 32                            // 2 clouds x 16 samples
#define NBINS 132                         // abs x-bin storage stride (used: 0..128)

// half-slab tile: 66 rows x 131 cols, +3 shift pad, rounded to float4 multiple
#define HROWS 66
#define HTILE_PAD 8652                    // 66*131=8646 -> +3 shift -> 8649 -> round to 8652

typedef float fx4 __attribute__((ext_vector_type(4)));   // nontemporal-store-compatible

// ---------------------------------------------------------------------------
// Kernel 1: fused per-axis min + x-histogram in ABSOLUTE bins.
// Absolute bin: floor(x*64) + 64 in [0,128] -- independent of mins, so the
// hist/scan/reorder chain has no dependency on the min reduction.
// 1024 threads/block, one (cloud,sample) per block (1024 | 32768).
// mins[3] pre-set to 0x7f7f7f7f; counts pre-set to 0.
// ---------------------------------------------------------------------------
__global__ void __launch_bounds__(1024)
min_hist_kernel(const float* __restrict__ pc,
                const float* __restrict__ gc,
                int* __restrict__ mins,
                int* __restrict__ counts) {
    __shared__ int h[NBINS];
    __shared__ int red[3 * 16];           // per-wave mins, 16 waves

    for (int t = threadIdx.x; t < NBINS; t += 1024) h[t] = 0;
    __syncthreads();

    int i = blockIdx.x * 1024 + threadIdx.x;       // i in [0, 2*BATCH*NPTS)
    const float s = SCALE * 0.5f;
    const float* src = (i < BATCH * NPTS) ? pc : gc;
    int j = (i < BATCH * NPTS) ? i : i - BATCH * NPTS;
    float x = src[3 * j + 0] * s;
    float y = src[3 * j + 1] * s;
    float z = src[3 * j + 2] * s;
    int lx = (int)floorf(x);
    int ly = (int)floorf(y);
    int lz = (int)floorf(z);

    // histogram (padding points masked; mins include ALL points, per reference)
    if (x + y + z != 0.0f) atomicAdd(&h[lx + 64], 1);

    // wave-64 min reduction
    int m0 = lx, m1 = ly, m2 = lz;
    #pragma unroll
    for (int off = 32; off > 0; off >>= 1) {
        m0 = min(m0, __shfl_down(m0, off));
        m1 = min(m1, __shfl_down(m1, off));
        m2 = min(m2, __shfl_down(m2, off));
    }
    int wave = threadIdx.x >> 6;
    if ((threadIdx.x & 63) == 0) {
        red[3 * wave + 0] = m0;
        red[3 * wave + 1] = m1;
        red[3 * wave + 2] = m2;
    }
    __syncthreads();

    if (threadIdx.x < 3) {
        int m = red[threadIdx.x];
        #pragma unroll
        for (int w = 1; w < 16; ++w) m = min(m, red[3 * w + threadIdx.x]);
        atomicMin(&mins[threadIdx.x], m);
    }

    // flush histogram
    int cb = blockIdx.x >> 5;             // 32 blocks per (cloud,sample)
    for (int t = threadIdx.x; t < NBINS; t += 1024) {
        int c = h[t];
        if (c) atomicAdd(&counts[cb * NBINS + t], c);
    }
}

// ---------------------------------------------------------------------------
// Kernel 2: per-(cloud,sample) exclusive prefix sum over NBINS abs bins.
// ---------------------------------------------------------------------------
__global__ void scan_kernel(const int* __restrict__ counts,
                            int* __restrict__ starts,
                            int* __restrict__ cursor) {
    int cb = threadIdx.x;
    if (cb >= NCB) return;
    int acc = 0;
    for (int bin = 0; bin < NBINS; ++bin) {
        starts[cb * (NBINS + 1) + bin] = acc;
        cursor[cb * NBINS + bin] = acc;
        acc += counts[cb * NBINS + bin];
    }
    starts[cb * (NBINS + 1) + NBINS] = acc;
}

// ---------------------------------------------------------------------------
// Kernel 3: reorder points into abs-bin-sorted payloads (no mins needed):
// float4(fx, fy, fz, bits((ly+64) | (lz+64)<<16)) at sorted[cb*NPTS + slot].
// ---------------------------------------------------------------------------
__global__ void reorder_kernel(const float* __restrict__ pc,
                               const float* __restrict__ gc,
                               int* __restrict__ cursor,
                               float4* __restrict__ sorted) {
    int i = blockIdx.x * blockDim.x + threadIdx.x;
    if (i >= 2 * BATCH * NPTS) return;
    const float s = SCALE * 0.5f;
    const float* src = (i < BATCH * NPTS) ? pc : gc;
    int j = (i < BATCH * NPTS) ? i : i - BATCH * NPTS;
    float x = src[3 * j + 0] * s;
    float y = src[3 * j + 1] * s;
    float z = src[3 * j + 2] * s;
    if (x + y + z == 0.0f) return;
    int lx = (int)floorf(x), ly = (int)floorf(y), lz = (int)floorf(z);
    float fx = x - (float)lx, fy = y - (float)ly, fz = z - (float)lz;
    int cb = i >> 15;
    int slot = atomicAdd(&cursor[cb * NBINS + (lx + 64)], 1);
    sorted[cb * NPTS + slot] =
        make_float4(fx, fy, fz, __int_as_float((ly + 64) | ((lz + 64) << 16)));
}

// ---------------------------------------------------------------------------
// Kernel 4 (reworked): gather. One 512-thread block per (cb, ix, y-half):
// accumulate a 66x131 (or 65x131) half-slab in LDS from abs bins
// (ix-2+minoffx) [w=fx] and (ix-1+minoffx) [w=1-fx], then stream the
// half-slab out once as float4 nontemporal stores (SHIFT-aligned).
// 34.6 KB LDS -> 4 blocks/CU (2048 threads = cap) -> 32 waves/CU with 4
// independently-phased blocks, so store/zero/atomic phases overlap across
// blocks and the HBM write pipe stays fed.
// ---------------------------------------------------------------------------
__global__ void __launch_bounds__(512, 8)
gather_kernel(const float4* __restrict__ sorted,
              const int* __restrict__ starts,
              const int* __restrict__ mins,
              float* __restrict__ out) {
    __shared__ __align__(16) float tile[HTILE_PAD];

    // bijective XCD-chunk swizzle: 8384 blocks = 8 * 1048 exactly.
    // consecutive logical blocks (both halves of a slab, neighboring ix)
    // land on the same XCD -> sorted/starts reads hit the same L2.
    int orig = blockIdx.x;
    int blk = (orig & 7) * 1048 + (orig >> 3);

    int h  = blk & 1;
    int t2 = blk >> 1;                    // cb*GRID_L + ix
    int cb = t2 / GRID_L;
    int ix = t2 - cb * GRID_L;

    int base = HROWS * h;                 // first slab row owned by this block
    int rows = h ? (GRID_L - HROWS) : HROWS;   // 65 : 66
    int N = rows * GRID_L;                // floats to emit
    int base_dw = cb * GRID_V + ix * SLAB + base * GRID_L;
    int SHIFT = base_dw & 3;              // tile shift so vector body is aligned
    int i0 = (4 - SHIFT) & 3;             // first out index with 16B alignment

    int minoffx = mins[0] + 64;           // abs-bin of the global min corner
    int minoffy = mins[1] + 64;
    int minoffz = mins[2] + 64;

    fx4* tz = (fx4*)tile;
    for (int t = threadIdx.x; t < HTILE_PAD / 4; t += 512)
        tz[t] = (fx4){0.0f, 0.0f, 0.0f, 0.0f};
    __syncthreads();

    const float4* pts = sorted + (size_t)cb * NPTS;
    const int* st = starts + cb * (NBINS + 1);

    #pragma unroll
    for (int pass = 0; pass < 2; ++pass) {
        int bin = ix - 2 + pass + minoffx;
        if (bin < 0 || bin >= NBINS) continue;
        int b0 = st[bin], b1 = st[bin + 1];
        for (int p = b0 + (int)threadIdx.x; p < b1; p += 512) {
            float4 q = pts[p];
            int pack = __float_as_int(q.w);
            int py = (pack & 0xffff) - minoffy + 1;   // lower y vertex, [1,128]
            int pz = (pack >> 16) - minoffz + 1;      // lower z vertex, [1,128]
            float wx  = pass ? (1.0f - q.x) : q.x;
            float wz0 = wx * (1.0f - q.z);
            float wz1 = wx * q.z;
            int r0 = py - base;                       // local row for (1-fy)
            if (r0 >= 0 && r0 < rows) {
                float wy0 = 1.0f - q.y;
                float* t0 = &tile[r0 * GRID_L + pz + SHIFT];
                atomicAdd(t0,     wy0 * wz0);
                atomicAdd(t0 + 1, wy0 * wz1);
            }
            int r1 = r0 + 1;                          // local row for fy
            if (r1 >= 0 && r1 < rows) {
                float wy1 = q.y;
                float* t1 = &tile[r1 * GRID_L + pz + SHIFT];
                atomicAdd(t1,     wy1 * wz0);
                atomicAdd(t1 + 1, wy1 * wz1);
            }
        }
    }
    __syncthreads();

    float* o = out + base_dw;
    // head peel (<=3 scalar stores) to reach 16B alignment
    if ((int)threadIdx.x < i0)
        __builtin_nontemporal_store(tile[threadIdx.x + SHIFT], &o[threadIdx.x]);
    // vector body: LDS source at tile[i0+SHIFT] is 16B aligned (i0+SHIFT is 0 or 4)
    int n4 = (N - i0) >> 2;
    const fx4* t4 = (const fx4*)&tile[i0 + SHIFT];
    fx4* o4 = (fx4*)&o[i0];
    for (int k = threadIdx.x; k < n4; k += 512)
        __builtin_nontemporal_store(t4[k], &o4[k]);
    // tail peel (<=3 scalar stores)
    int tail0 = i0 + 4 * n4;
    int tt = tail0 + (int)threadIdx.x;
    if (tt < N)
        __builtin_nontemporal_store(tile[tt + SHIFT], &o[tt]);
}

extern "C" void kernel_launch(void* const* d_in, const int* in_sizes, int n_in,
                              void* d_out, int out_size, void* d_ws, size_t ws_size,
                              hipStream_t stream) {
    const float* pred = (const float*)d_in[0];
    const float* gt   = (const float*)d_in[1];
    float* out = (float*)d_out;   // [2, BATCH, GRID_V]: pred grids then gt grids

    // workspace layout
    char* w = (char*)d_ws;
    int* mins   = (int*)w;                         // 3 ints
    int* counts = (int*)(w + 16);                  // NCB*NBINS
    int* starts = counts + NCB * NBINS;            // NCB*(NBINS+1)
    int* cursor = starts + NCB * (NBINS + 1);      // NCB*NBINS
    size_t off = 16 + sizeof(int) * (size_t)(NCB * NBINS + NCB * (NBINS + 1) + NCB * NBINS);
    off = (off + 15) & ~(size_t)15;
    float4* sorted = (float4*)(w + off);           // NCB*NPTS float4 = 16 MB

    hipMemsetAsync(mins, 0x7f, 3 * sizeof(int), stream);
    hipMemsetAsync(counts, 0, sizeof(int) * NCB * NBINS, stream);

    const int total2 = 2 * BATCH * NPTS;           // 1,048,576
    min_hist_kernel<<<total2 / 1024, 1024, 0, stream>>>(pred, gt, mins, counts);
    scan_kernel<<<1, 64, 0, stream>>>(counts, starts, cursor);
    reorder_kernel<<<(total2 + 255) / 256, 256, 0, stream>>>(pred, gt, cursor, sorted);
    gather_kernel<<<NCB * GRID_L * 2, 512, 0, stream>>>(sorted, starts, mins, out);
}

// Round 3
// 375.910 us; speedup vs baseline: 1.1410x; 1.1339x over previous
//
#include <hip/hip_runtime.h>

#define SCALE 128
#define GRID_L 131                        // grid side
#define SLAB (GRID_L * GRID_L)            // 17161 floats per x-slab
#define GRID_V (GRID_L * GRID_L * GRID_L)
#define BATCH 16
#define NPTS 32768                        // points per sample (2^15)
#define NCB 32                            // 2 clouds x 16 samples
#define NBINS 132                         // abs x-bin storage stride (used: 0..128)

// half-slab tile: 66 rows x 131 cols, +3 shift pad, rounded to float4 multiple
#define HROWS 66
#define HTILE_PAD 8652                    // 66*131=8646 -> +3 shift -> 8649 -> round to 8652

typedef float fx4 __attribute__((ext_vector_type(4)));   // nontemporal-store-compatible

// ---------------------------------------------------------------------------
// Kernel 1: fused per-axis min + x-histogram in ABSOLUTE bins.
// 4 points/thread via 3x float4 loads (48B/thread). 256 blocks x 1024 thr.
// Absolute bin: floor(x*64) + 64 in [0,128] -- independent of mins.
// mins[3] pre-set to 0x7f7f7f7f; counts pre-set to 0.
// ---------------------------------------------------------------------------
__global__ void __launch_bounds__(1024)
min_hist_kernel(const float* __restrict__ pc,
                const float* __restrict__ gc,
                int* __restrict__ mins,
                int* __restrict__ counts) {
    __shared__ int h[NBINS];
    __shared__ int red[3 * 16];           // per-wave mins, 16 waves

    for (int t = threadIdx.x; t < NBINS; t += 1024) h[t] = 0;
    __syncthreads();

    const float s = SCALE * 0.5f;
    int blk = blockIdx.x;                          // 256 blocks, 4096 pts each
    const float* src = (blk < 128) ? pc : gc;
    int jbase = (blk & 127) * 4096;
    const fx4* p4 = (const fx4*)(src + (size_t)3 * jbase);
    int t3 = 3 * (int)threadIdx.x;
    fx4 a = p4[t3], b = p4[t3 + 1], c = p4[t3 + 2];

    float xs[4] = {a.x, a.w, b.z, c.y};
    float ys[4] = {a.y, b.x, b.w, c.z};
    float zs[4] = {a.z, b.y, c.x, c.w};
    int m0 = 0x7fffffff, m1 = 0x7fffffff, m2 = 0x7fffffff;
    #pragma unroll
    for (int k = 0; k < 4; ++k) {
        float x = xs[k] * s, y = ys[k] * s, z = zs[k] * s;
        int lx = (int)floorf(x), ly = (int)floorf(y), lz = (int)floorf(z);
        // histogram (padding points masked; mins include ALL points, per ref)
        if (x + y + z != 0.0f) atomicAdd(&h[lx + 64], 1);
        m0 = min(m0, lx); m1 = min(m1, ly); m2 = min(m2, lz);
    }

    // wave-64 min reduction
    #pragma unroll
    for (int off = 32; off > 0; off >>= 1) {
        m0 = min(m0, __shfl_down(m0, off));
        m1 = min(m1, __shfl_down(m1, off));
        m2 = min(m2, __shfl_down(m2, off));
    }
    int wave = threadIdx.x >> 6;
    if ((threadIdx.x & 63) == 0) {
        red[3 * wave + 0] = m0;
        red[3 * wave + 1] = m1;
        red[3 * wave + 2] = m2;
    }
    __syncthreads();

    if (threadIdx.x < 3) {
        int m = red[threadIdx.x];
        #pragma unroll
        for (int w = 1; w < 16; ++w) m = min(m, red[3 * w + threadIdx.x]);
        atomicMin(&mins[threadIdx.x], m);
    }

    // flush histogram; 8 blocks per (cloud,sample)
    int cb = (blk >> 7) * 16 + ((blk & 127) >> 3);
    for (int t = threadIdx.x; t < NBINS; t += 1024) {
        int c = h[t];
        if (c) atomicAdd(&counts[cb * NBINS + t], c);
    }
}

// ---------------------------------------------------------------------------
// Kernel 2: per-(cloud,sample) exclusive prefix sum over NBINS abs bins.
// ---------------------------------------------------------------------------
__global__ void scan_kernel(const int* __restrict__ counts,
                            int* __restrict__ starts,
                            int* __restrict__ cursor) {
    int cb = threadIdx.x;
    if (cb >= NCB) return;
    int acc = 0;
    #pragma unroll 4
    for (int bin = 0; bin < NBINS; ++bin) {
        starts[cb * (NBINS + 1) + bin] = acc;
        cursor[cb * NBINS + bin] = acc;
        acc += counts[cb * NBINS + bin];
    }
    starts[cb * (NBINS + 1) + NBINS] = acc;
}

// ---------------------------------------------------------------------------
// Kernel 3: reorder points into abs-bin-sorted payloads (no mins needed):
// float4(fx, fy, fz, bits((ly+64) | (lz+64)<<16)) at sorted[cb*NPTS + slot].
// 4 points/thread via 3x float4 loads. 1024 blocks x 256 thr.
// ---------------------------------------------------------------------------
__global__ void __launch_bounds__(256)
reorder_kernel(const float* __restrict__ pc,
               const float* __restrict__ gc,
               int* __restrict__ cursor,
               float4* __restrict__ sorted) {
    int gtid = blockIdx.x * 256 + threadIdx.x;     // 262144 threads, 4 pts each
    const float s = SCALE * 0.5f;
    const float* src = (gtid < 131072) ? pc : gc;
    int q = gtid & 131071;
    const fx4* p4 = (const fx4*)src;
    fx4 a = p4[3 * q], b = p4[3 * q + 1], c = p4[3 * q + 2];

    int cb = (gtid * 4) >> 15;            // all 4 points share one cb
    float4* dst = sorted + (size_t)cb * NPTS;
    int* cur = cursor + cb * NBINS;

    float xs[4] = {a.x, a.w, b.z, c.y};
    float ys[4] = {a.y, b.x, b.w, c.z};
    float zs[4] = {a.z, b.y, c.x, c.w};
    #pragma unroll
    for (int k = 0; k < 4; ++k) {
        float x = xs[k] * s, y = ys[k] * s, z = zs[k] * s;
        if (x + y + z == 0.0f) continue;
        int lx = (int)floorf(x), ly = (int)floorf(y), lz = (int)floorf(z);
        float fx = x - (float)lx, fy = y - (float)ly, fz = z - (float)lz;
        int slot = atomicAdd(&cur[lx + 64], 1);
        dst[slot] =
            make_float4(fx, fy, fz, __int_as_float((ly + 64) | ((lz + 64) << 16)));
    }
}

// ---------------------------------------------------------------------------
// Kernel 4: gather. One 512-thread block per (cb, ix, y-half): accumulate a
// 66x131 (or 65x131) half-slab in LDS from abs bins (ix-2+minoffx) [w=fx]
// and (ix-1+minoffx) [w=1-fx], then stream the half-slab out once as float4
// nontemporal stores (SHIFT-aligned). No min-waves clause: avoid a 64-VGPR
// cap that could force spills; LDS 34.6KB allows up to 4 blocks/CU.
// ---------------------------------------------------------------------------
__global__ void __launch_bounds__(512)
gather_kernel(const float4* __restrict__ sorted,
              const int* __restrict__ starts,
              const int* __restrict__ mins,
              float* __restrict__ out) {
    __shared__ __align__(16) float tile[HTILE_PAD];

    // bijective XCD-chunk swizzle: 8384 blocks = 8 * 1048 exactly.
    int orig = blockIdx.x;
    int blk = (orig & 7) * 1048 + (orig >> 3);

    int h  = blk & 1;
    int t2 = blk >> 1;                    // cb*GRID_L + ix
    int cb = t2 / GRID_L;
    int ix = t2 - cb * GRID_L;

    int base = HROWS * h;                 // first slab row owned by this block
    int rows = h ? (GRID_L - HROWS) : HROWS;   // 65 : 66
    int N = rows * GRID_L;                // floats to emit
    int base_dw = cb * GRID_V + ix * SLAB + base * GRID_L;
    int SHIFT = base_dw & 3;              // tile shift so vector body is aligned
    int i0 = (4 - SHIFT) & 3;             // first out index with 16B alignment

    int minoffx = mins[0] + 64;           // abs-bin of the global min corner
    int minoffy = mins[1] + 64;
    int minoffz = mins[2] + 64;

    fx4* tz = (fx4*)tile;
    for (int t = threadIdx.x; t < HTILE_PAD / 4; t += 512)
        tz[t] = (fx4){0.0f, 0.0f, 0.0f, 0.0f};
    __syncthreads();

    const float4* pts = sorted + (size_t)cb * NPTS;
    const int* st = starts + cb * (NBINS + 1);

    #pragma unroll
    for (int pass = 0; pass < 2; ++pass) {
        int bin = ix - 2 + pass + minoffx;
        if (bin < 0 || bin >= NBINS) continue;
        int b0 = st[bin], b1 = st[bin + 1];
        for (int p = b0 + (int)threadIdx.x; p < b1; p += 512) {
            float4 q = pts[p];
            int pack = __float_as_int(q.w);
            int py = (pack & 0xffff) - minoffy + 1;   // lower y vertex, [1,128]
            int pz = (pack >> 16) - minoffz + 1;      // lower z vertex, [1,128]
            float wx  = pass ? (1.0f - q.x) : q.x;
            float wz0 = wx * (1.0f - q.z);
            float wz1 = wx * q.z;
            int r0 = py - base;                       // local row for (1-fy)
            if (r0 >= 0 && r0 < rows) {
                float wy0 = 1.0f - q.y;
                float* t0 = &tile[r0 * GRID_L + pz + SHIFT];
                atomicAdd(t0,     wy0 * wz0);
                atomicAdd(t0 + 1, wy0 * wz1);
            }
            int r1 = r0 + 1;                          // local row for fy
            if (r1 >= 0 && r1 < rows) {
                float wy1 = q.y;
                float* t1 = &tile[r1 * GRID_L + pz + SHIFT];
                atomicAdd(t1,     wy1 * wz0);
                atomicAdd(t1 + 1, wy1 * wz1);
            }
        }
    }
    __syncthreads();

    float* o = out + base_dw;
    // head peel (<=3 scalar stores) to reach 16B alignment
    if ((int)threadIdx.x < i0)
        __builtin_nontemporal_store(tile[threadIdx.x + SHIFT], &o[threadIdx.x]);
    // vector body: LDS source at tile[i0+SHIFT] is 16B aligned
    int n4 = (N - i0) >> 2;
    const fx4* t4 = (const fx4*)&tile[i0 + SHIFT];
    fx4* o4 = (fx4*)&o[i0];
    for (int k = threadIdx.x; k < n4; k += 512)
        __builtin_nontemporal_store(t4[k], &o4[k]);
    // tail peel (<=3 scalar stores)
    int tail0 = i0 + 4 * n4;
    int tt = tail0 + (int)threadIdx.x;
    if (tt < N)
        __builtin_nontemporal_store(tile[tt + SHIFT], &o[tt]);
}

extern "C" void kernel_launch(void* const* d_in, const int* in_sizes, int n_in,
                              void* d_out, int out_size, void* d_ws, size_t ws_size,
                              hipStream_t stream) {
    const float* pred = (const float*)d_in[0];
    const float* gt   = (const float*)d_in[1];
    float* out = (float*)d_out;   // [2, BATCH, GRID_V]: pred grids then gt grids

    // workspace layout
    char* w = (char*)d_ws;
    int* mins   = (int*)w;                         // 3 ints
    int* counts = (int*)(w + 16);                  // NCB*NBINS
    int* starts = counts + NCB * NBINS;            // NCB*(NBINS+1)
    int* cursor = starts + NCB * (NBINS + 1);      // NCB*NBINS
    size_t off = 16 + sizeof(int) * (size_t)(NCB * NBINS + NCB * (NBINS + 1) + NCB * NBINS);
    off = (off + 15) & ~(size_t)15;
    float4* sorted = (float4*)(w + off);           // NCB*NPTS float4 = 16 MB

    hipMemsetAsync(mins, 0x7f, 3 * sizeof(int), stream);
    hipMemsetAsync(counts, 0, sizeof(int) * NCB * NBINS, stream);

    min_hist_kernel<<<256, 1024, 0, stream>>>(pred, gt, mins, counts);
    scan_kernel<<<1, 64, 0, stream>>>(counts, starts, cursor);
    reorder_kernel<<<1024, 256, 0, stream>>>(pred, gt, cursor, sorted);
    gather_kernel<<<NCB * GRID_L * 2, 512, 0, stream>>>(sorted, starts, mins, out);
}